// Round 14
// baseline (646.375 us; speedup 1.0000x reference)
//
#include <hip/hip_runtime.h>
#include <stdint.h>

#define BB 64
#define NN 4096
#define DD 256
#define SS 8
#define NITER 3
#define NCHUNK 8
#define EPS_LN 1e-5f
#define EPS_ATTN 1e-8f

typedef __attribute__((ext_vector_type(4))) float fvec4;
typedef __attribute__((ext_vector_type(8))) __bf16 bf16x8;
typedef __attribute__((ext_vector_type(8))) unsigned short usvec8;
typedef __attribute__((ext_vector_type(4))) unsigned short usvec4;

__device__ __forceinline__ float bf2f(unsigned short u) {
  return __uint_as_float(((unsigned)u) << 16);
}
__device__ __forceinline__ unsigned short f2bf(float f) {
  unsigned u = __float_as_uint(f);
  u += 0x7FFFu + ((u >> 16) & 1u);
  return (unsigned short)(u >> 16);
}
__device__ __forceinline__ void async_copy16(void* ldsp, const void* gp) {
  __builtin_amdgcn_global_load_lds(
      (const __attribute__((address_space(1))) unsigned int*)gp,
      (__attribute__((address_space(3))) unsigned int*)ldsp, 16, 0, 0);
}

// ---------------- init: slots broadcast + zero both colsum buffers ----------------
__global__ void k_sinit(const float* __restrict__ slots_init, float* __restrict__ slots,
                        float* __restrict__ colsum) {
  int b = blockIdx.x, t = threadIdx.x;
  const fvec4* src = (const fvec4*)slots_init;
  fvec4* dst = (fvec4*)(slots + (size_t)b * SS * DD);
  for (int j = t; j < SS * DD / 4; j += 256) dst[j] = src[j];
  if (t < SS) {
    colsum[b * SS + t] = 0.f;
    colsum[BB * SS + b * SS + t] = 0.f;
  }
}

// ---------------- prep: WkT[dk][m] = Wk[m][dk] (tiled transpose) ----------------
__global__ void k_wprepT(const float* __restrict__ Wk, float* __restrict__ WkT) {
  __shared__ float tile[16][17];
  int bx = blockIdx.x, by = blockIdx.y, t = threadIdx.x;
  int r = t >> 4, c = t & 15;
  tile[r][c] = Wk[(size_t)(by * 16 + r) * DD + bx * 16 + c];
  __syncthreads();
  WkT[(size_t)(bx * 16 + r) * DD + by * 16 + c] = tile[c][r];
}

// ---------------- prep: combined q-side transforms (scale folded in) ----------------
__launch_bounds__(256)
__global__ void k_wcomb(const float* __restrict__ Wq, const float* __restrict__ WkT,
                        const float* __restrict__ bq, const float* __restrict__ bk,
                        float* __restrict__ Wqk, float* __restrict__ bqk,
                        float* __restrict__ wqbk, float* __restrict__ bqbk) {
  __shared__ float wqrow[DD];
  __shared__ float red[4];
  const float sc = 0.0625f;
  int j = blockIdx.x, t = threadIdx.x;
  wqrow[t] = Wq[(size_t)j * DD + t];
  __syncthreads();
  float a = 0.f;
#pragma unroll 4
  for (int dk = 0; dk < DD; dk++) a += wqrow[dk] * WkT[(size_t)dk * DD + t];
  Wqk[(size_t)j * DD + t] = a * sc;
  float c = wqrow[t] * bk[t];
#pragma unroll
  for (int m = 32; m >= 1; m >>= 1) c += __shfl_xor(c, m);
  if ((t & 63) == 0) red[t >> 6] = c;
  __syncthreads();
  if (t == 0) wqbk[j] = sc * (red[0] + red[1] + red[2] + red[3]);
  if (j == 0) {
    float bb = 0.f;
#pragma unroll 4
    for (int dk = 0; dk < DD; dk++) bb += bq[dk] * WkT[(size_t)dk * DD + t];
    bqk[t] = bb * sc;
    __syncthreads();
    float c2 = bq[t] * bk[t];
#pragma unroll
    for (int m = 32; m >= 1; m >>= 1) c2 += __shfl_xor(c2, m);
    if ((t & 63) == 0) red[t >> 6] = c2;
    __syncthreads();
    if (t == 0) bqbk[0] = sc * (red[0] + red[1] + red[2] + red[3]);
  }
}

// ---------------- A1: x = LN(inputs)*g+b -> bf16 (coalesced) ----------------
__launch_bounds__(256)
__global__ void k_lnx(const float* __restrict__ in, const float* __restrict__ g,
                      const float* __restrict__ bt, unsigned short* __restrict__ xbf) {
  int t = threadIdx.x;
  long row = (long)blockIdx.x * 32 + (t >> 3);
  int u = t & 7;
  const float* rp = in + row * DD;
  fvec4 v[8];
  float s = 0.f, s2 = 0.f;
#pragma unroll
  for (int j = 0; j < 8; j++) {
    v[j] = *(const fvec4*)(rp + j * 32 + u * 4);
    s += v[j].x + v[j].y + v[j].z + v[j].w;
    s2 += v[j].x * v[j].x + v[j].y * v[j].y + v[j].z * v[j].z + v[j].w * v[j].w;
  }
  s += __shfl_xor(s, 1); s2 += __shfl_xor(s2, 1);
  s += __shfl_xor(s, 2); s2 += __shfl_xor(s2, 2);
  s += __shfl_xor(s, 4); s2 += __shfl_xor(s2, 4);
  float mu = s / DD;
  float rs = rsqrtf(s2 / DD - mu * mu + EPS_LN);
#pragma unroll
  for (int j = 0; j < 8; j++) {
    fvec4 gg = *(const fvec4*)(g + j * 32 + u * 4);
    fvec4 bb = *(const fvec4*)(bt + j * 32 + u * 4);
    usvec4 o;
    o[0] = f2bf((v[j].x - mu) * rs * gg.x + bb.x);
    o[1] = f2bf((v[j].y - mu) * rs * gg.y + bb.y);
    o[2] = f2bf((v[j].z - mu) * rs * gg.z + bb.z);
    o[3] = f2bf((v[j].w - mu) * rs * gg.w + bb.w);
    *(usvec4*)&xbf[row * DD + j * 32 + u * 4] = o;
  }
}

// ---------------- fused: LN_s + qk/qb (redundant per block) + MFMA attn + PV ----------------
__launch_bounds__(256, 2)
__global__ void k_attn2q(const unsigned short* __restrict__ xbf,
                         const float* __restrict__ slots,
                         const float* __restrict__ g_s, const float* __restrict__ b_s,
                         const float* __restrict__ Wqk, const float* __restrict__ bqk,
                         const float* __restrict__ wqbk, const float* __restrict__ bqbk,
                         const int* __restrict__ mask,
                         float* __restrict__ colsum, float* __restrict__ upart) {
  __shared__ __attribute__((aligned(16))) unsigned short kt[2][64 * 256];  // 64 KB
  __shared__ float aL[2][64 * 9];                                          // 4.5 KB
  __shared__ float snq[SS][DD];                                            // 8 KB: sn, then qk
  __shared__ float qbp[4][SS];
  __shared__ float qbL[SS];
  int b = blockIdx.y, chunk = blockIdx.x, t = threadIdx.x;
  int w = t >> 6, lane = t & 63;
  int n_base = chunk * 512;
  int cl15 = lane & 15, hg = lane >> 4;
  int ns = t >> 5;

  auto stage = [&](int c, int bb) {
    int r0 = n_base + c * 64;
#pragma unroll
    for (int j = 0; j < 8; j++) {
      int gidx = w * 512 + j * 64 + lane;
      int row = gidx >> 5, c16 = gidx & 31;
      async_copy16(&kt[bb][gidx * 8],
                   xbf + ((size_t)(b * NN + r0 + row)) * DD + ((c16 ^ (row & 7)) * 8));
    }
  };
  stage(0, 0);  // prefetch first x tile; Q phase below overlaps it

  // ---- Q phase: LN_s(slots) -> snq ----
  {
    int row = t >> 5, seg = t & 31;
    const float* sp = slots + (size_t)(b * SS + row) * DD + seg * 8;
    float v[8], s = 0.f, s2 = 0.f;
#pragma unroll
    for (int e = 0; e < 8; e++) { v[e] = sp[e]; s += v[e]; s2 += v[e] * v[e]; }
#pragma unroll
    for (int m = 16; m >= 1; m >>= 1) { s += __shfl_xor(s, m); s2 += __shfl_xor(s2, m); }
    float mu = s / DD, rs = rsqrtf(s2 / DD - mu * mu + EPS_LN);
#pragma unroll
    for (int e = 0; e < 8; e++) {
      int d = seg * 8 + e;
      snq[row][d] = (v[e] - mu) * rs * g_s[d] + b_s[d];
    }
  }
  __syncthreads();
  // qb partials
  {
    float wb = wqbk[t];
    float c8[SS];
#pragma unroll
    for (int i = 0; i < SS; i++) c8[i] = snq[i][t] * wb;
#pragma unroll
    for (int m = 32; m >= 1; m >>= 1)
#pragma unroll
      for (int i = 0; i < SS; i++) c8[i] += __shfl_xor(c8[i], m);
    if (lane == 0) {
#pragma unroll
      for (int i = 0; i < SS; i++) qbp[w][i] = c8[i];
    }
  }
  // qk = sn @ Wqk + bqk (full, col t per thread)
  float qacc[SS];
  {
    float b0 = bqk[t];
#pragma unroll
    for (int i = 0; i < SS; i++) qacc[i] = b0;
#pragma unroll 8
    for (int k = 0; k < DD; k += 4) {
      float w0 = Wqk[(size_t)(k + 0) * DD + t];
      float w1 = Wqk[(size_t)(k + 1) * DD + t];
      float w2 = Wqk[(size_t)(k + 2) * DD + t];
      float w3 = Wqk[(size_t)(k + 3) * DD + t];
#pragma unroll
      for (int i = 0; i < SS; i++) {
        fvec4 sv = *(const fvec4*)&snq[i][k];
        qacc[i] += sv.x * w0 + sv.y * w1 + sv.z * w2 + sv.w * w3;
      }
    }
  }
  __syncthreads();  // all snq reads done
#pragma unroll
  for (int i = 0; i < SS; i++) snq[i][t] = qacc[i];  // snq now holds qk
  if (t < SS) qbL[t] = qbp[0][t] + qbp[1][t] + qbp[2][t] + qbp[3][t] + bqbk[0];
  __syncthreads();

  // ---- build qf fragments from snq(=qk) ----
  bf16x8 qf[8];
  {
    int qrow = cl15 < 8 ? cl15 : 0;
    const float* qp = &snq[qrow][0];
#pragma unroll
    for (int kst = 0; kst < 8; kst++) {
      int d0 = kst * 32 + hg * 8;
      usvec8 uq;
      if (cl15 < 8) {
        fvec4 q0 = *(const fvec4*)(qp + d0);
        fvec4 q1 = *(const fvec4*)(qp + d0 + 4);
        uq[0] = f2bf(q0.x); uq[1] = f2bf(q0.y); uq[2] = f2bf(q0.z); uq[3] = f2bf(q0.w);
        uq[4] = f2bf(q1.x); uq[5] = f2bf(q1.y); uq[6] = f2bf(q1.z); uq[7] = f2bf(q1.w);
      } else {
        uq = (usvec8)0;
      }
      qf[kst] = __builtin_bit_cast(bf16x8, uq);
    }
  }
  float qadd[4];
#pragma unroll
  for (int e = 0; e < 4; e++) qadd[e] = qbL[(hg & 1) * 4 + e];

  float acc[SS][8] = {};
  float csum[4] = {};

  for (int c = 0; c < 8; c++) {
    int bb = c & 1, pb = c & 1;
    int r0 = n_base + c * 64;
    if (c < 7) {
      stage(c + 1, bb ^ 1);
      asm volatile("s_waitcnt vmcnt(8)" ::: "memory");
    } else {
      asm volatile("s_waitcnt vmcnt(0)" ::: "memory");
    }
    __builtin_amdgcn_sched_barrier(0);
    fvec4 S = {0.f, 0.f, 0.f, 0.f};
    int row_l = w * 16 + cl15;
#pragma unroll
    for (int kst = 0; kst < 8; kst++) {
      int c16 = (kst * 4 + hg) ^ (row_l & 7);
      bf16x8 bfk = *(const bf16x8*)&kt[bb][row_l * 256 + c16 * 8];
      S = __builtin_amdgcn_mfma_f32_16x16x32_bf16(qf[kst], bfk, S, 0, 0, 0);
    }
    S[0] += qadd[0]; S[1] += qadd[1]; S[2] += qadd[2]; S[3] += qadd[3];
    {
      float m4 = fmaxf(fmaxf(S[0], S[1]), fmaxf(S[2], S[3]));
      float mo = __shfl_xor(m4, 16);
      float mx = fmaxf(m4, mo);
      float e0 = __expf(S[0] - mx), e1 = __expf(S[1] - mx);
      float e2 = __expf(S[2] - mx), e3 = __expf(S[3] - mx);
      float s4 = e0 + e1 + e2 + e3;
      float so = __shfl_xor(s4, 16);
      float inv = 1.f / (s4 + so);
      int mk = mask[(size_t)b * NN + r0 + row_l];
      float a0 = mk ? 0.125f : e0 * inv;
      float a1 = mk ? 0.125f : e1 * inv;
      float a2 = mk ? 0.125f : e2 * inv;
      float a3 = mk ? 0.125f : e3 * inv;
      if (lane < 32) {
        csum[0] += a0; csum[1] += a1; csum[2] += a2; csum[3] += a3;
        float* ap = &aL[pb][(w * 16 + cl15) * 9 + hg * 4];
        ap[0] = a0; ap[1] = a1; ap[2] = a2; ap[3] = a3;
      }
    }
    __syncthreads();
#pragma unroll
    for (int s8 = 0; s8 < 8; s8++) {
      int r = s8 * 8 + ns;
      usvec8 vv = *(const usvec8*)&kt[bb][r * 256 + (((t & 31)) ^ (r & 7)) * 8];
      float vf[8];
#pragma unroll
      for (int e = 0; e < 8; e++) vf[e] = bf2f(vv[e]);
#pragma unroll
      for (int i = 0; i < SS; i++) {
        float aw = aL[pb][r * 9 + i];
#pragma unroll
        for (int e = 0; e < 8; e++) acc[i][e] += aw * vf[e];
      }
    }
    __syncthreads();
  }
#pragma unroll
  for (int m = 1; m <= 8; m <<= 1)
#pragma unroll
    for (int e = 0; e < 4; e++) csum[e] += __shfl_xor(csum[e], m);
  if (lane == 0) {
#pragma unroll
    for (int e = 0; e < 4; e++) atomicAdd(&colsum[b * SS + e], csum[e]);
  } else if (lane == 16) {
#pragma unroll
    for (int e = 0; e < 4; e++) atomicAdd(&colsum[b * SS + 4 + e], csum[e]);
  }
#pragma unroll
  for (int i = 0; i < SS; i++)
#pragma unroll
    for (int e = 0; e < 8; e++) acc[i][e] += __shfl_xor(acc[i][e], 32);
  __syncthreads();
  float* red = (float*)&kt[0][0];  // [4][SS][DD]
  if (lane < 32) {
#pragma unroll
    for (int i = 0; i < SS; i++) {
      fvec4 a0 = {acc[i][0], acc[i][1], acc[i][2], acc[i][3]};
      fvec4 a1 = {acc[i][4], acc[i][5], acc[i][6], acc[i][7]};
      *(fvec4*)&red[(w * SS + i) * DD + lane * 8] = a0;
      *(fvec4*)&red[(w * SS + i) * DD + lane * 8 + 4] = a1;
    }
  }
  __syncthreads();
  int i2 = t >> 5, dsg = (t & 31) * 8;
  float* up = upart + ((size_t)(b * NCHUNK + chunk)) * (SS * DD) + i2 * DD + dsg;
#pragma unroll
  for (int e = 0; e < 8; e++)
    up[e] = red[(0 * SS + i2) * DD + dsg + e] + red[(1 * SS + i2) * DD + dsg + e] +
            red[(2 * SS + i2) * DD + dsg + e] + red[(3 * SS + i2) * DD + dsg + e];
}

// ---------------- fused slot-side: y-sum -> Wv(full) -> sn -> LN_m -> W1(full)+relu -> W2 slice ----------------
__launch_bounds__(256, 2)
__global__ void k_slotmlp(const float* __restrict__ slots_rd, float* __restrict__ slots_wr,
                          const float* __restrict__ upart,
                          const float* __restrict__ Wv, const float* __restrict__ bv,
                          const float* __restrict__ colsum_rd, float* __restrict__ colsum_z,
                          const float* __restrict__ g_m, const float* __restrict__ b_m,
                          const float* __restrict__ W1, const float* __restrict__ b1,
                          const float* __restrict__ W2, const float* __restrict__ b2) {
  __shared__ float yL[SS][DD];   // y; later reused as part[8][SS][32]
  __shared__ float snL[SS][DD];
  __shared__ float hL[SS][DD];
  __shared__ float h2L[SS][DD];
  int b = blockIdx.x, cg = blockIdx.y, t = threadIdx.x;
  if (cg == 0 && t < SS) colsum_z[b * SS + t] = 0.f;
  // 1. y = chunk-sum
#pragma unroll
  for (int i = 0; i < SS; i++) {
    float s = 0.f;
#pragma unroll
    for (int c = 0; c < NCHUNK; c++)
      s += upart[((size_t)(b * NCHUNK + c)) * (SS * DD) + i * DD + t];
    yL[i][t] = s;
  }
  __syncthreads();
  // 2. full Wv GEMM (col t) -> sn
  {
    float a[SS] = {};
#pragma unroll 8
    for (int k = 0; k < DD; k += 4) {
      float w0 = Wv[(size_t)(k + 0) * DD + t];
      float w1 = Wv[(size_t)(k + 1) * DD + t];
      float w2 = Wv[(size_t)(k + 2) * DD + t];
      float w3 = Wv[(size_t)(k + 3) * DD + t];
#pragma unroll
      for (int i = 0; i < SS; i++) {
        fvec4 yv = *(const fvec4*)&yL[i][k];
        a[i] += yv.x * w0 + yv.y * w1 + yv.z * w2 + yv.w * w3;
      }
    }
    float bvt = bv[t];
#pragma unroll
    for (int i = 0; i < SS; i++) {
      float cs = colsum_rd[b * SS + i];
      float csinv = 1.f / (cs + EPS_ATTN);
      snL[i][t] = slots_rd[(size_t)(b * SS + i) * DD + t] + (a[i] + bvt * cs) * csinv;
    }
  }
  __syncthreads();
  // 3. LN_m(sn) -> hL
  {
    int row = t >> 5, seg = t & 31;
    float v[8], s = 0.f, s2 = 0.f;
#pragma unroll
    for (int e = 0; e < 8; e++) { v[e] = snL[row][seg * 8 + e]; s += v[e]; s2 += v[e] * v[e]; }
#pragma unroll
    for (int m = 16; m >= 1; m >>= 1) { s += __shfl_xor(s, m); s2 += __shfl_xor(s2, m); }
    float mu = s / DD, rs = rsqrtf(s2 / DD - mu * mu + EPS_LN);
#pragma unroll
    for (int e = 0; e < 8; e++) {
      int d = seg * 8 + e;
      hL[row][d] = (v[e] - mu) * rs * g_m[d] + b_m[d];
    }
  }
  __syncthreads();
  // 4. full W1 GEMM + relu -> h2
  {
    float a[SS] = {};
#pragma unroll 8
    for (int k = 0; k < DD; k += 4) {
      float w0 = W1[(size_t)(k + 0) * DD + t];
      float w1 = W1[(size_t)(k + 1) * DD + t];
      float w2 = W1[(size_t)(k + 2) * DD + t];
      float w3 = W1[(size_t)(k + 3) * DD + t];
#pragma unroll
      for (int i = 0; i < SS; i++) {
        fvec4 hv = *(const fvec4*)&hL[i][k];
        a[i] += hv.x * w0 + hv.y * w1 + hv.z * w2 + hv.w * w3;
      }
    }
    float b1t = b1[t];
#pragma unroll
    for (int i = 0; i < SS; i++) h2L[i][t] = fmaxf(a[i] + b1t, 0.f);
  }
  __syncthreads();
  // 5. W2 slice GEMM (32 cols, 8-way k-split; reuse yL as part)
  float (*part)[SS][32] = (float(*)[SS][32]) & yL[0][0];
  {
    int kq = t >> 5, c = t & 31;
    int colg = cg * 32 + c;
    float a[SS] = {};
#pragma unroll 8
    for (int kk = 0; kk < 32; kk++) {
      int k = kq * 32 + kk;
      float wv = W2[(size_t)k * DD + colg];
#pragma unroll
      for (int i = 0; i < SS; i++) a[i] += h2L[i][k] * wv;
    }
#pragma unroll
    for (int i = 0; i < SS; i++) part[kq][i][c] = a[i];
  }
  __syncthreads();
  {
    int i = t >> 5, c2 = t & 31;
    float s = 0.f;
#pragma unroll
    for (int kq2 = 0; kq2 < 8; kq2++) s += part[kq2][i][c2];
    int cg2 = cg * 32 + c2;
    slots_wr[(size_t)(b * SS + i) * DD + cg2] = snL[i][cg2] + s + b2[cg2];
  }
}

// ---------------- final LN -> out ----------------
__launch_bounds__(256)
__global__ void k_out(const float* __restrict__ slots, const float* __restrict__ g_o,
                      const float* __restrict__ b_o, float* __restrict__ out) {
  int b = blockIdx.x, t = threadIdx.x;
  int row = t >> 5, seg = t & 31;
  const float* sp = slots + (size_t)(b * SS + row) * DD + seg * 8;
  float v[8];
  float s = 0.f, s2 = 0.f;
#pragma unroll
  for (int e = 0; e < 8; e++) { v[e] = sp[e]; s += v[e]; s2 += v[e] * v[e]; }
#pragma unroll
  for (int m = 16; m >= 1; m >>= 1) { s += __shfl_xor(s, m); s2 += __shfl_xor(s2, m); }
  float mu = s / DD;
  float rs = rsqrtf(s2 / DD - mu * mu + EPS_LN);
#pragma unroll
  for (int e = 0; e < 8; e++) {
    int d = seg * 8 + e;
    out[(size_t)(b * SS + row) * DD + d] = (v[e] - mu) * rs * g_o[d] + b_o[d];
  }
}

extern "C" void kernel_launch(void* const* d_in, const int* in_sizes, int n_in,
                              void* d_out, int out_size, void* d_ws, size_t ws_size,
                              hipStream_t stream) {
  (void)in_sizes; (void)n_in; (void)out_size; (void)ws_size;
  const float* inputs = (const float*)d_in[0];
  const int* mask = (const int*)d_in[1];
  const float* slots_init = (const float*)d_in[2];
  const float* g_in = (const float*)d_in[3];
  const float* b_in = (const float*)d_in[4];
  const float* g_s = (const float*)d_in[5];
  const float* b_s = (const float*)d_in[6];
  const float* g_m = (const float*)d_in[7];
  const float* b_m = (const float*)d_in[8];
  const float* g_o = (const float*)d_in[9];
  const float* b_o = (const float*)d_in[10];
  const float* Wq = (const float*)d_in[11];
  const float* bq = (const float*)d_in[12];
  const float* Wk = (const float*)d_in[13];
  const float* bk = (const float*)d_in[14];
  const float* Wv = (const float*)d_in[15];
  const float* bv = (const float*)d_in[16];
  const float* W1 = (const float*)d_in[17];
  const float* b1 = (const float*)d_in[18];
  const float* W2 = (const float*)d_in[19];
  const float* b2 = (const float*)d_in[20];
  float* out = (float*)d_out;

  char* ws = (char*)d_ws;
  size_t off = 0;
  auto alloc = [&](size_t bytes) -> void* {
    void* p = ws + off;
    off += (bytes + 255) & ~(size_t)255;
    return p;
  };
  unsigned short* xbf = (unsigned short*)alloc((size_t)BB * NN * DD * 2);
  float* WkT = (float*)alloc((size_t)DD * DD * 4);
  float* Wqk = (float*)alloc((size_t)DD * DD * 4);
  float* bqk = (float*)alloc((size_t)DD * 4);
  float* wqbk = (float*)alloc((size_t)DD * 4);
  float* bqbk = (float*)alloc(4);
  float* slots = (float*)alloc((size_t)2 * BB * SS * DD * 4);   // ping-pong
  float* upart = (float*)alloc((size_t)BB * NCHUNK * SS * DD * 4);
  float* colsum = (float*)alloc((size_t)2 * BB * SS * 4);       // ping-pong

  const size_t SLOT_SZ = (size_t)BB * SS * DD;
  const size_t CS_SZ = (size_t)BB * SS;

  k_sinit<<<dim3(BB), dim3(256), 0, stream>>>(slots_init, slots, colsum);
  k_wprepT<<<dim3(16, 16), dim3(256), 0, stream>>>(Wk, WkT);
  k_wcomb<<<dim3(DD), dim3(256), 0, stream>>>(Wq, WkT, bq, bk, Wqk, bqk, wqbk, bqbk);
  k_lnx<<<dim3(BB * NN / 32), dim3(256), 0, stream>>>(inputs, g_in, b_in, xbf);

  for (int it = 0; it < NITER; ++it) {
    float* cs_rd = colsum + (size_t)(it & 1) * CS_SZ;
    float* cs_z = colsum + (size_t)((it + 1) & 1) * CS_SZ;
    const float* sl_rd = slots + (size_t)(it & 1) * SLOT_SZ;
    float* sl_wr = slots + (size_t)((it + 1) & 1) * SLOT_SZ;
    k_attn2q<<<dim3(NCHUNK, BB), dim3(256), 0, stream>>>(
        xbf, sl_rd, g_s, b_s, Wqk, bqk, wqbk, bqbk, mask, cs_rd, upart);
    k_slotmlp<<<dim3(BB, 8), dim3(256), 0, stream>>>(
        sl_rd, sl_wr, upart, Wv, bv, cs_rd, cs_z, g_m, b_m, W1, b1, W2, b2);
  }
  k_out<<<dim3(BB), dim3(256), 0, stream>>>(slots + (NITER & 1) * SLOT_SZ, g_o, b_o, out);
}

// Round 15
// 391.574 us; speedup vs baseline: 1.6507x; 1.6507x over previous
//
#include <hip/hip_runtime.h>
#include <stdint.h>

#define BB 64
#define NN 4096
#define DD 256
#define SS 8
#define NITER 3
#define NCHUNK 8
#define EPS_LN 1e-5f
#define EPS_ATTN 1e-8f

typedef __attribute__((ext_vector_type(4))) float fvec4;
typedef __attribute__((ext_vector_type(8))) __bf16 bf16x8;
typedef __attribute__((ext_vector_type(8))) unsigned short usvec8;
typedef __attribute__((ext_vector_type(4))) unsigned short usvec4;

__device__ __forceinline__ float bf2f(unsigned short u) {
  return __uint_as_float(((unsigned)u) << 16);
}
__device__ __forceinline__ unsigned short f2bf(float f) {
  unsigned u = __float_as_uint(f);
  u += 0x7FFFu + ((u >> 16) & 1u);
  return (unsigned short)(u >> 16);
}
__device__ __forceinline__ void async_copy16(void* ldsp, const void* gp) {
  __builtin_amdgcn_global_load_lds(
      (const __attribute__((address_space(1))) unsigned int*)gp,
      (__attribute__((address_space(3))) unsigned int*)ldsp, 16, 0, 0);
}

// ---------------- init: slots broadcast ----------------
__global__ void k_sinit(const float* __restrict__ slots_init, float* __restrict__ slots) {
  int b = blockIdx.x, t = threadIdx.x;
  const fvec4* src = (const fvec4*)slots_init;
  fvec4* dst = (fvec4*)(slots + (size_t)b * SS * DD);
  for (int j = t; j < SS * DD / 4; j += 256) dst[j] = src[j];
}

// ---------------- prep: WkT[dk][m] = Wk[m][dk] (tiled transpose) ----------------
__global__ void k_wprepT(const float* __restrict__ Wk, float* __restrict__ WkT) {
  __shared__ float tile[16][17];
  int bx = blockIdx.x, by = blockIdx.y, t = threadIdx.x;
  int r = t >> 4, c = t & 15;
  tile[r][c] = Wk[(size_t)(by * 16 + r) * DD + bx * 16 + c];
  __syncthreads();
  WkT[(size_t)(bx * 16 + r) * DD + by * 16 + c] = tile[c][r];
}

// ---------------- prep: combined q-side transforms (scale folded in) ----------------
__launch_bounds__(256)
__global__ void k_wcomb(const float* __restrict__ Wq, const float* __restrict__ WkT,
                        const float* __restrict__ bq, const float* __restrict__ bk,
                        float* __restrict__ Wqk, float* __restrict__ bqk,
                        float* __restrict__ wqbk, float* __restrict__ bqbk) {
  __shared__ float wqrow[DD];
  __shared__ float red[4];
  const float sc = 0.0625f;
  int j = blockIdx.x, t = threadIdx.x;
  wqrow[t] = Wq[(size_t)j * DD + t];
  __syncthreads();
  float a = 0.f;
#pragma unroll 4
  for (int dk = 0; dk < DD; dk++) a += wqrow[dk] * WkT[(size_t)dk * DD + t];
  Wqk[(size_t)j * DD + t] = a * sc;
  float c = wqrow[t] * bk[t];
#pragma unroll
  for (int m = 32; m >= 1; m >>= 1) c += __shfl_xor(c, m);
  if ((t & 63) == 0) red[t >> 6] = c;
  __syncthreads();
  if (t == 0) wqbk[j] = sc * (red[0] + red[1] + red[2] + red[3]);
  if (j == 0) {
    float bb = 0.f;
#pragma unroll 4
    for (int dk = 0; dk < DD; dk++) bb += bq[dk] * WkT[(size_t)dk * DD + t];
    bqk[t] = bb * sc;
    __syncthreads();
    float c2 = bq[t] * bk[t];
#pragma unroll
    for (int m = 32; m >= 1; m >>= 1) c2 += __shfl_xor(c2, m);
    if ((t & 63) == 0) red[t >> 6] = c2;
    __syncthreads();
    if (t == 0) bqbk[0] = sc * (red[0] + red[1] + red[2] + red[3]);
  }
}

// ---------------- A1: x = LN(inputs)*g+b -> bf16 (coalesced) ----------------
__launch_bounds__(256)
__global__ void k_lnx(const float* __restrict__ in, const float* __restrict__ g,
                      const float* __restrict__ bt, unsigned short* __restrict__ xbf) {
  int t = threadIdx.x;
  long row = (long)blockIdx.x * 32 + (t >> 3);
  int u = t & 7;
  const float* rp = in + row * DD;
  fvec4 v[8];
  float s = 0.f, s2 = 0.f;
#pragma unroll
  for (int j = 0; j < 8; j++) {
    v[j] = *(const fvec4*)(rp + j * 32 + u * 4);
    s += v[j].x + v[j].y + v[j].z + v[j].w;
    s2 += v[j].x * v[j].x + v[j].y * v[j].y + v[j].z * v[j].z + v[j].w * v[j].w;
  }
  s += __shfl_xor(s, 1); s2 += __shfl_xor(s2, 1);
  s += __shfl_xor(s, 2); s2 += __shfl_xor(s2, 2);
  s += __shfl_xor(s, 4); s2 += __shfl_xor(s2, 4);
  float mu = s / DD;
  float rs = rsqrtf(s2 / DD - mu * mu + EPS_LN);
#pragma unroll
  for (int j = 0; j < 8; j++) {
    fvec4 gg = *(const fvec4*)(g + j * 32 + u * 4);
    fvec4 bb = *(const fvec4*)(bt + j * 32 + u * 4);
    usvec4 o;
    o[0] = f2bf((v[j].x - mu) * rs * gg.x + bb.x);
    o[1] = f2bf((v[j].y - mu) * rs * gg.y + bb.y);
    o[2] = f2bf((v[j].z - mu) * rs * gg.z + bb.z);
    o[3] = f2bf((v[j].w - mu) * rs * gg.w + bb.w);
    *(usvec4*)&xbf[row * DD + j * 32 + u * 4] = o;
  }
}

// ---------------- I1: s = LN(slots); qk 32-col slice (8-way ksplit); qb; zero colsum ----------------
__launch_bounds__(256, 2)
__global__ void k_slotq2(const float* __restrict__ slots, const float* __restrict__ g_s,
                         const float* __restrict__ b_s, const float* __restrict__ Wqk,
                         const float* __restrict__ bqk, const float* __restrict__ wqbk,
                         const float* __restrict__ bqbk, float* __restrict__ qk,
                         float* __restrict__ qb, float* __restrict__ colsum) {
  __shared__ float sl[SS][DD];
  __shared__ float part[8][SS][32];
  __shared__ float qbp[4][SS];
  int b = blockIdx.x, cg = blockIdx.y, t = threadIdx.x;
  if (cg == 0 && t < SS) colsum[b * SS + t] = 0.f;
  int row = t >> 5, seg = t & 31;
  {
    const float* sp = slots + (size_t)(b * SS + row) * DD + seg * 8;
    float v[8];
    float s = 0.f, s2 = 0.f;
#pragma unroll
    for (int e = 0; e < 8; e++) { v[e] = sp[e]; s += v[e]; s2 += v[e] * v[e]; }
#pragma unroll
    for (int m = 16; m >= 1; m >>= 1) { s += __shfl_xor(s, m); s2 += __shfl_xor(s2, m); }
    float mu = s / DD;
    float rs = rsqrtf(s2 / DD - mu * mu + EPS_LN);
#pragma unroll
    for (int e = 0; e < 8; e++) {
      int d = seg * 8 + e;
      sl[row][d] = (v[e] - mu) * rs * g_s[d] + b_s[d];
    }
  }
  __syncthreads();
  if (cg == 0) {
    float wb = wqbk[t];
    float c8[SS];
#pragma unroll
    for (int i = 0; i < SS; i++) c8[i] = sl[i][t] * wb;
#pragma unroll
    for (int m = 32; m >= 1; m >>= 1)
#pragma unroll
      for (int i = 0; i < SS; i++) c8[i] += __shfl_xor(c8[i], m);
    if ((t & 63) == 0) {
#pragma unroll
      for (int i = 0; i < SS; i++) qbp[t >> 6][i] = c8[i];
    }
  }
  int kq = t >> 5, c = t & 31;
  int colg = cg * 32 + c;
  float a[SS] = {};
#pragma unroll 8
  for (int kk = 0; kk < 32; kk++) {
    int k = kq * 32 + kk;
    float wv = Wqk[(size_t)k * DD + colg];
#pragma unroll
    for (int i = 0; i < SS; i++) a[i] += sl[i][k] * wv;
  }
#pragma unroll
  for (int i = 0; i < SS; i++) part[kq][i][c] = a[i];
  __syncthreads();
  {
    int i = t >> 5, c2 = t & 31;
    float s = 0.f;
#pragma unroll
    for (int kq2 = 0; kq2 < 8; kq2++) s += part[kq2][i][c2];
    int cg2 = cg * 32 + c2;
    qk[(size_t)(b * SS + i) * DD + cg2] = s + bqk[cg2];
  }
  if (cg == 0 && t < SS)
    qb[b * SS + t] = qbp[0][t] + qbp[1][t] + qbp[2][t] + qbp[3][t] + bqbk[0];
}

// ---------------- I2+I3: MFMA qk.x^T (LDS-staged x) -> slot-softmax -> LDS PV ----------------
__launch_bounds__(256, 2)
__global__ void k_attn2(const unsigned short* __restrict__ xbf,
                        const float* __restrict__ qkb, const float* __restrict__ qb,
                        const int* __restrict__ mask,
                        float* __restrict__ colsum, float* __restrict__ upart) {
  __shared__ __attribute__((aligned(16))) unsigned short kt[2][64 * 256];  // 2x32KB swizzled x
  __shared__ float aL[2][64 * 9];                                          // attn weights
  int b = blockIdx.y, chunk = blockIdx.x, t = threadIdx.x;
  int w = t >> 6, lane = t & 63;
  int n_base = chunk * 512;
  int cl15 = lane & 15, hg = lane >> 4;

  bf16x8 qf[8];
  {
    int qrow = cl15 < 8 ? cl15 : 0;
    const float* qp = qkb + (size_t)(b * SS + qrow) * DD;
#pragma unroll
    for (int kst = 0; kst < 8; kst++) {
      int d0 = kst * 32 + hg * 8;
      usvec8 uq;
      if (cl15 < 8) {
        fvec4 q0 = *(const fvec4*)(qp + d0);
        fvec4 q1 = *(const fvec4*)(qp + d0 + 4);
        uq[0] = f2bf(q0.x); uq[1] = f2bf(q0.y); uq[2] = f2bf(q0.z); uq[3] = f2bf(q0.w);
        uq[4] = f2bf(q1.x); uq[5] = f2bf(q1.y); uq[6] = f2bf(q1.z); uq[7] = f2bf(q1.w);
      } else {
        uq = (usvec8)0;
      }
      qf[kst] = __builtin_bit_cast(bf16x8, uq);
    }
  }
  float qadd[4];
#pragma unroll
  for (int e = 0; e < 4; e++) qadd[e] = qb[b * SS + (hg & 1) * 4 + e];

  float acc[SS][8] = {};
  float csum[4] = {};
  int ns = t >> 5;

  auto stage = [&](int c, int bb) {
    int r0 = n_base + c * 64;
#pragma unroll
    for (int j = 0; j < 8; j++) {
      int gidx = w * 512 + j * 64 + lane;
      int row = gidx >> 5, c16 = gidx & 31;
      async_copy16(&kt[bb][gidx * 8],
                   xbf + ((size_t)(b * NN + r0 + row)) * DD + ((c16 ^ (row & 7)) * 8));
    }
  };

  stage(0, 0);
  for (int c = 0; c < 8; c++) {
    int bb = c & 1, pb = c & 1;
    int r0 = n_base + c * 64;
    if (c < 7) {
      stage(c + 1, bb ^ 1);
      asm volatile("s_waitcnt vmcnt(8)" ::: "memory");
    } else {
      asm volatile("s_waitcnt vmcnt(0)" ::: "memory");
    }
    __builtin_amdgcn_sched_barrier(0);
    fvec4 S = {0.f, 0.f, 0.f, 0.f};
    int row_l = w * 16 + cl15;
#pragma unroll
    for (int kst = 0; kst < 8; kst++) {
      int c16 = (kst * 4 + hg) ^ (row_l & 7);
      bf16x8 bfk = *(const bf16x8*)&kt[bb][row_l * 256 + c16 * 8];
      S = __builtin_amdgcn_mfma_f32_16x16x32_bf16(qf[kst], bfk, S, 0, 0, 0);
    }
    S[0] += qadd[0]; S[1] += qadd[1]; S[2] += qadd[2]; S[3] += qadd[3];
    {
      float m4 = fmaxf(fmaxf(S[0], S[1]), fmaxf(S[2], S[3]));
      float mo = __shfl_xor(m4, 16);
      float mx = fmaxf(m4, mo);
      float e0 = __expf(S[0] - mx), e1 = __expf(S[1] - mx);
      float e2 = __expf(S[2] - mx), e3 = __expf(S[3] - mx);
      float s4 = e0 + e1 + e2 + e3;
      float so = __shfl_xor(s4, 16);
      float inv = 1.f / (s4 + so);
      int mk = mask[(size_t)b * NN + r0 + row_l];
      float a0 = mk ? 0.125f : e0 * inv;
      float a1 = mk ? 0.125f : e1 * inv;
      float a2 = mk ? 0.125f : e2 * inv;
      float a3 = mk ? 0.125f : e3 * inv;
      if (lane < 32) {
        csum[0] += a0; csum[1] += a1; csum[2] += a2; csum[3] += a3;
        float* ap = &aL[pb][(w * 16 + cl15) * 9 + hg * 4];
        ap[0] = a0; ap[1] = a1; ap[2] = a2; ap[3] = a3;
      }
    }
    __syncthreads();
#pragma unroll
    for (int s8 = 0; s8 < 8; s8++) {
      int r = s8 * 8 + ns;
      usvec8 vv = *(const usvec8*)&kt[bb][r * 256 + (((t & 31)) ^ (r & 7)) * 8];
      float vf[8];
#pragma unroll
      for (int e = 0; e < 8; e++) vf[e] = bf2f(vv[e]);
#pragma unroll
      for (int i = 0; i < SS; i++) {
        float aw = aL[pb][r * 9 + i];
#pragma unroll
        for (int e = 0; e < 8; e++) acc[i][e] += aw * vf[e];
      }
    }
    __syncthreads();
  }
#pragma unroll
  for (int m = 1; m <= 8; m <<= 1)
#pragma unroll
    for (int e = 0; e < 4; e++) csum[e] += __shfl_xor(csum[e], m);
  if (lane == 0) {
#pragma unroll
    for (int e = 0; e < 4; e++) atomicAdd(&colsum[b * SS + e], csum[e]);
  } else if (lane == 16) {
#pragma unroll
    for (int e = 0; e < 4; e++) atomicAdd(&colsum[b * SS + 4 + e], csum[e]);
  }
#pragma unroll
  for (int i = 0; i < SS; i++)
#pragma unroll
    for (int e = 0; e < 8; e++) acc[i][e] += __shfl_xor(acc[i][e], 32);
  __syncthreads();
  float* red = (float*)&kt[0][0];  // [4][SS][DD]
  if (lane < 32) {
#pragma unroll
    for (int i = 0; i < SS; i++) {
      fvec4 a0 = {acc[i][0], acc[i][1], acc[i][2], acc[i][3]};
      fvec4 a1 = {acc[i][4], acc[i][5], acc[i][6], acc[i][7]};
      *(fvec4*)&red[(w * SS + i) * DD + lane * 8] = a0;
      *(fvec4*)&red[(w * SS + i) * DD + lane * 8 + 4] = a1;
    }
  }
  __syncthreads();
  int i2 = t >> 5, dsg = (t & 31) * 8;
  float* up = upart + ((size_t)(b * NCHUNK + chunk)) * (SS * DD) + i2 * DD + dsg;
#pragma unroll
  for (int e = 0; e < 8; e++)
    up[e] = red[(0 * SS + i2) * DD + dsg + e] + red[(1 * SS + i2) * DD + dsg + e] +
            red[(2 * SS + i2) * DD + dsg + e] + red[(3 * SS + i2) * DD + dsg + e];
}

// ---------------- I3b: y=sum(upart); sn slice = slots + (y@Wv + bv*cs)*csinv ----------------
__launch_bounds__(256, 2)
__global__ void k_updv(const float* __restrict__ slots, const float* __restrict__ upart,
                       const float* __restrict__ Wv, const float* __restrict__ bv,
                       const float* __restrict__ colsum, float* __restrict__ snbuf) {
  __shared__ float yL[SS][DD];
  __shared__ float part[8][SS][32];
  int b = blockIdx.x, cg = blockIdx.y, t = threadIdx.x;
  {
    int i = t >> 5, seg = t & 31;
    fvec4 sa = {0.f, 0.f, 0.f, 0.f}, sb = {0.f, 0.f, 0.f, 0.f};
#pragma unroll
    for (int c = 0; c < NCHUNK; c++) {
      const float* up = upart + ((size_t)(b * NCHUNK + c)) * (SS * DD) + i * DD + seg * 8;
      fvec4 u0 = *(const fvec4*)up;
      fvec4 u1 = *(const fvec4*)(up + 4);
      sa.x += u0.x; sa.y += u0.y; sa.z += u0.z; sa.w += u0.w;
      sb.x += u1.x; sb.y += u1.y; sb.z += u1.z; sb.w += u1.w;
    }
    *(fvec4*)&yL[i][seg * 8] = sa;
    *(fvec4*)&yL[i][seg * 8 + 4] = sb;
  }
  __syncthreads();
  int kq = t >> 5, c = t & 31;
  int colg = cg * 32 + c;
  float a[SS] = {};
#pragma unroll 8
  for (int kk = 0; kk < 32; kk++) {
    int k = kq * 32 + kk;
    float wv = Wv[(size_t)k * DD + colg];
#pragma unroll
    for (int i = 0; i < SS; i++) a[i] += yL[i][k] * wv;
  }
#pragma unroll
  for (int i = 0; i < SS; i++) part[kq][i][c] = a[i];
  __syncthreads();
  {
    int i = t >> 5, c2 = t & 31;
    float s = 0.f;
#pragma unroll
    for (int kq2 = 0; kq2 < 8; kq2++) s += part[kq2][i][c2];
    int cg2 = cg * 32 + c2;
    float cs = colsum[b * SS + i];
    float csinv = 1.f / (cs + EPS_ATTN);
    size_t idx = (size_t)(b * SS + i) * DD + cg2;
    snbuf[idx] = slots[idx] + (s + bv[cg2] * cs) * csinv;
  }
}

// ---------------- I4a: LN_m(sn) -> h; h2 slice = relu(h@W1+b1) ----------------
__launch_bounds__(256, 2)
__global__ void k_mlp1(const float* __restrict__ snbuf, const float* __restrict__ g_m,
                       const float* __restrict__ b_m, const float* __restrict__ W1,
                       const float* __restrict__ b1, float* __restrict__ h2g) {
  __shared__ float hL[SS][DD];
  __shared__ float part[8][SS][32];
  int b = blockIdx.x, cg = blockIdx.y, t = threadIdx.x;
  int row = t >> 5, seg = t & 31;
  {
    const float* sp = snbuf + (size_t)(b * SS + row) * DD + seg * 8;
    float v[8], s = 0.f, s2 = 0.f;
#pragma unroll
    for (int e = 0; e < 8; e++) { v[e] = sp[e]; s += v[e]; s2 += v[e] * v[e]; }
#pragma unroll
    for (int m = 16; m >= 1; m >>= 1) { s += __shfl_xor(s, m); s2 += __shfl_xor(s2, m); }
    float mu = s / DD;
    float rs = rsqrtf(s2 / DD - mu * mu + EPS_LN);
#pragma unroll
    for (int e = 0; e < 8; e++) {
      int d = seg * 8 + e;
      hL[row][d] = (v[e] - mu) * rs * g_m[d] + b_m[d];
    }
  }
  __syncthreads();
  int kq = t >> 5, c = t & 31;
  int colg = cg * 32 + c;
  float a[SS] = {};
#pragma unroll 8
  for (int kk = 0; kk < 32; kk++) {
    int k = kq * 32 + kk;
    float wv = W1[(size_t)k * DD + colg];
#pragma unroll
    for (int i = 0; i < SS; i++) a[i] += hL[i][k] * wv;
  }
#pragma unroll
  for (int i = 0; i < SS; i++) part[kq][i][c] = a[i];
  __syncthreads();
  {
    int i = t >> 5, c2 = t & 31;
    float s = 0.f;
#pragma unroll
    for (int kq2 = 0; kq2 < 8; kq2++) s += part[kq2][i][c2];
    int cg2 = cg * 32 + c2;
    h2g[(size_t)(b * SS + i) * DD + cg2] = fmaxf(s + b1[cg2], 0.f);
  }
}

// ---------------- I4b: slots slice = sn + h2@W2 + b2 ----------------
__launch_bounds__(256, 2)
__global__ void k_mlp2(float* __restrict__ slots, const float* __restrict__ snbuf,
                       const float* __restrict__ h2g, const float* __restrict__ W2,
                       const float* __restrict__ b2) {
  __shared__ float h2L[SS][DD];
  __shared__ float part[8][SS][32];
  int b = blockIdx.x, cg = blockIdx.y, t = threadIdx.x;
  {
    const fvec4* src = (const fvec4*)(h2g + (size_t)b * SS * DD);
    fvec4* dst = (fvec4*)h2L;
    for (int j = t; j < SS * DD / 4; j += 256) dst[j] = src[j];
  }
  __syncthreads();
  int kq = t >> 5, c = t & 31;
  int colg = cg * 32 + c;
  float a[SS] = {};
#pragma unroll 8
  for (int kk = 0; kk < 32; kk++) {
    int k = kq * 32 + kk;
    float wv = W2[(size_t)k * DD + colg];
#pragma unroll
    for (int i = 0; i < SS; i++) a[i] += h2L[i][k] * wv;
  }
#pragma unroll
  for (int i = 0; i < SS; i++) part[kq][i][c] = a[i];
  __syncthreads();
  {
    int i = t >> 5, c2 = t & 31;
    float s = 0.f;
#pragma unroll
    for (int kq2 = 0; kq2 < 8; kq2++) s += part[kq2][i][c2];
    int cg2 = cg * 32 + c2;
    size_t idx = (size_t)(b * SS + i) * DD + cg2;
    slots[idx] = snbuf[idx] + s + b2[cg2];
  }
}

// ---------------- final LN -> out ----------------
__launch_bounds__(256)
__global__ void k_out(const float* __restrict__ slots, const float* __restrict__ g_o,
                      const float* __restrict__ b_o, float* __restrict__ out) {
  int b = blockIdx.x, t = threadIdx.x;
  int row = t >> 5, seg = t & 31;
  const float* sp = slots + (size_t)(b * SS + row) * DD + seg * 8;
  float v[8];
  float s = 0.f, s2 = 0.f;
#pragma unroll
  for (int e = 0; e < 8; e++) { v[e] = sp[e]; s += v[e]; s2 += v[e] * v[e]; }
#pragma unroll
  for (int m = 16; m >= 1; m >>= 1) { s += __shfl_xor(s, m); s2 += __shfl_xor(s2, m); }
  float mu = s / DD;
  float rs = rsqrtf(s2 / DD - mu * mu + EPS_LN);
#pragma unroll
  for (int e = 0; e < 8; e++) {
    int d = seg * 8 + e;
    out[(size_t)(b * SS + row) * DD + d] = (v[e] - mu) * rs * g_o[d] + b_o[d];
  }
}

extern "C" void kernel_launch(void* const* d_in, const int* in_sizes, int n_in,
                              void* d_out, int out_size, void* d_ws, size_t ws_size,
                              hipStream_t stream) {
  (void)in_sizes; (void)n_in; (void)out_size; (void)ws_size;
  const float* inputs = (const float*)d_in[0];
  const int* mask = (const int*)d_in[1];
  const float* slots_init = (const float*)d_in[2];
  const float* g_in = (const float*)d_in[3];
  const float* b_in = (const float*)d_in[4];
  const float* g_s = (const float*)d_in[5];
  const float* b_s = (const float*)d_in[6];
  const float* g_m = (const float*)d_in[7];
  const float* b_m = (const float*)d_in[8];
  const float* g_o = (const float*)d_in[9];
  const float* b_o = (const float*)d_in[10];
  const float* Wq = (const float*)d_in[11];
  const float* bq = (const float*)d_in[12];
  const float* Wk = (const float*)d_in[13];
  const float* bk = (const float*)d_in[14];
  const float* Wv = (const float*)d_in[15];
  const float* bv = (const float*)d_in[16];
  const float* W1 = (const float*)d_in[17];
  const float* b1 = (const float*)d_in[18];
  const float* W2 = (const float*)d_in[19];
  const float* b2 = (const float*)d_in[20];
  float* out = (float*)d_out;

  char* ws = (char*)d_ws;
  size_t off = 0;
  auto alloc = [&](size_t bytes) -> void* {
    void* p = ws + off;
    off += (bytes + 255) & ~(size_t)255;
    return p;
  };
  unsigned short* xbf = (unsigned short*)alloc((size_t)BB * NN * DD * 2);
  float* WkT = (float*)alloc((size_t)DD * DD * 4);
  float* Wqk = (float*)alloc((size_t)DD * DD * 4);
  float* bqk = (float*)alloc((size_t)DD * 4);
  float* wqbk = (float*)alloc((size_t)DD * 4);
  float* bqbk = (float*)alloc(4);
  float* qk = (float*)alloc((size_t)BB * SS * DD * 4);
  float* qb = (float*)alloc((size_t)BB * SS * 4);
  float* slots = (float*)alloc((size_t)BB * SS * DD * 4);
  float* snbuf = (float*)alloc((size_t)BB * SS * DD * 4);
  float* h2g = (float*)alloc((size_t)BB * SS * DD * 4);
  float* upart = (float*)alloc((size_t)BB * NCHUNK * SS * DD * 4);
  float* colsum = (float*)alloc((size_t)BB * SS * 4);

  k_sinit<<<dim3(BB), dim3(256), 0, stream>>>(slots_init, slots);
  k_wprepT<<<dim3(16, 16), dim3(256), 0, stream>>>(Wk, WkT);
  k_wcomb<<<dim3(DD), dim3(256), 0, stream>>>(Wq, WkT, bq, bk, Wqk, bqk, wqbk, bqbk);
  k_lnx<<<dim3(BB * NN / 32), dim3(256), 0, stream>>>(inputs, g_in, b_in, xbf);

  for (int it = 0; it < NITER; ++it) {
    k_slotq2<<<dim3(BB, 8), dim3(256), 0, stream>>>(slots, g_s, b_s, Wqk, bqk, wqbk, bqbk,
                                                    qk, qb, colsum);
    k_attn2<<<dim3(NCHUNK, BB), dim3(256), 0, stream>>>(xbf, qk, qb, mask, colsum, upart);
    k_updv<<<dim3(BB, 8), dim3(256), 0, stream>>>(slots, upart, Wv, bv, colsum, snbuf);
    k_mlp1<<<dim3(BB, 8), dim3(256), 0, stream>>>(snbuf, g_m, b_m, W1, b1, h2g);
    k_mlp2<<<dim3(BB, 8), dim3(256), 0, stream>>>(slots, snbuf, h2g, W2, b2);
  }
  k_out<<<dim3(BB), dim3(256), 0, stream>>>(slots, g_o, b_o, out);
}